// Round 9
// baseline (186.840 us; speedup 1.0000x reference)
//
#include <hip/hip_runtime.h>
#include <stdint.h>

#define TEMP 0.25f   // 1/sqrt(d), d=16

typedef unsigned short u16;
typedef short v8s __attribute__((ext_vector_type(8)));
typedef float v4f __attribute__((ext_vector_type(4)));

static __device__ __forceinline__ uint32_t f2b_bits(float f){
    union { float f; uint32_t i; } x; x.f = f;
    uint32_t u = x.i;
    return (u + 0x7FFFu + ((u >> 16) & 1u)) >> 16;   // RNE to bf16 (as u16)
}
static __device__ __forceinline__ float b2f(u16 u){
    union { uint32_t i; float f; } x; x.i = ((uint32_t)u) << 16; return x.f;
}
static __device__ __forceinline__ float bl(uint32_t u){
    union { uint32_t i; float f; } x; x.i = u << 16; return x.f;
}
static __device__ __forceinline__ float bh(uint32_t u){
    union { uint32_t i; float f; } x; x.i = u & 0xffff0000u; return x.f;
}
static __device__ __forceinline__ uint4 pack8(const uint32_t* e){
    return make_uint4(e[0] | (e[1] << 16), e[2] | (e[3] << 16),
                      e[4] | (e[5] << 16), e[6] | (e[7] << 16));
}
// trunc-hi + RNE-lo two-term bf16 split, packed u0|u1<<16 in ONE cvt op.
static __device__ __forceinline__ uint32_t split2_pk(float x){
    float hi = __uint_as_float(__float_as_uint(x) & 0xffff0000u);
    float lo = x - hi;                       // exact
    uint32_t pk;
    asm("v_cvt_pk_bf16_f32 %0, %1, %2" : "=v"(pk) : "v"(hi), "v"(lo));
    return pk;                                // lo16=trunc(x), hi16=RNE(resid)
}
union U8S { uint4 u; v8s s; };
union I4S { int i[4]; v8s s; };
static __device__ __forceinline__ v8s asv8s(uint4 u){ U8S x; x.u = u; return x.s; }

// ---- DPP helpers: full 16-lane (row) reductions, no DS-pipe traffic.
template<int C>
static __device__ __forceinline__ float dppf(float x){
    int xi = __float_as_int(x);
    return __int_as_float(__builtin_amdgcn_update_dpp(xi, xi, C, 0xf, 0xf, false));
}
static __device__ __forceinline__ float red16_max(float m){
    m = fmaxf(m, dppf<0xB1>(m));  m = fmaxf(m, dppf<0x4E>(m));
    m = fmaxf(m, dppf<0x141>(m)); m = fmaxf(m, dppf<0x140>(m));
    return m;
}
static __device__ __forceinline__ float red16_sum(float s){
    s += dppf<0xB1>(s);  s += dppf<0x4E>(s);
    s += dppf<0x141>(s); s += dppf<0x140>(s);
    return s;
}
static __device__ __forceinline__ float sw16(float x){
    return __int_as_float(__builtin_amdgcn_ds_swizzle(__float_as_int(x), 0x401F));
}
template<int C>
static __device__ __forceinline__ uint64_t dppmax64(uint64_t k){
    int hi = (int)(uint32_t)(k >> 32), lo = (int)(uint32_t)k;
    uint32_t oh = (uint32_t)__builtin_amdgcn_update_dpp(hi, hi, C, 0xf, 0xf, false);
    uint32_t ol = (uint32_t)__builtin_amdgcn_update_dpp(lo, lo, C, 0xf, 0xf, false);
    uint64_t ok = ((uint64_t)oh << 32) | ol;
    return ok > k ? ok : k;
}
static __device__ __forceinline__ uint64_t red16_maxkey(uint64_t k){
    k = dppmax64<0xB1>(k);  k = dppmax64<0x4E>(k);
    k = dppmax64<0x141>(k); k = dppmax64<0x140>(k);
    return k;
}

// ---------------------------------------------------------------------------
// pack_coarse: K -> KP1=[K0|K1], KP3=[K2|K0]; V -> VP1=[V0|V1].
// ---------------------------------------------------------------------------
__global__ __launch_bounds__(256)
void pack_coarse(const float* __restrict__ kc, const float* __restrict__ vc,
                 uint4* __restrict__ KP1, uint4* __restrict__ KP3,
                 uint4* __restrict__ VP1)
{
    const int bh = blockIdx.x;        // 0..31
    const int kv = blockIdx.y;        // 0:K 1:V
    const int z  = blockIdx.z;        // 0..7 (8 kt each)
    const int b = bh >> 3, h = bh & 7;
    const int tid = threadIdx.x;
    const size_t sbase = (size_t)(b * 128 + h * 16) * 1024;
    const size_t fbase = (size_t)bh * 64 * 64;

    #pragma unroll
    for (int it = 0; it < 2; ++it){
        int task = it * 256 + tid;
        int kt = z * 8 + (task >> 6), ln = task & 63;
        int quad = ln >> 4, col = ln & 15;
        if (kv == 0){
            uint32_t e1[8], e3[8];
            #pragma unroll
            for (int j = 0; j < 8; ++j){
                int dch = (quad & 1) * 8 + j;
                float x = kc[sbase + (size_t)dch * 1024 + kt * 16 + col];
                uint32_t u0 = f2b_bits(x);
                float r1 = x - b2f((u16)u0);
                uint32_t u1 = f2b_bits(r1);
                float r2 = r1 - b2f((u16)u1);
                uint32_t u2 = f2b_bits(r2);
                e1[j] = (quad < 2) ? u0 : u1;
                e3[j] = (quad < 2) ? u2 : u0;
            }
            KP1[fbase + kt * 64 + ln] = pack8(e1);
            KP3[fbase + kt * 64 + ln] = pack8(e3);
        } else {
            uint32_t e[8];
            #pragma unroll
            for (int j = 0; j < 8; ++j){
                int key = kt * 16 + (quad & 1) * 8 + j;
                float x = vc[sbase + (size_t)col * 1024 + key];
                uint32_t pk = split2_pk(x);          // (trunc, RNE) packed
                e[j] = (quad < 2) ? (pk & 0xffffu) : (pk >> 16);
            }
            VP1[fbase + kt * 64 + ln] = pack8(e);
        }
    }
}

// ---------------------------------------------------------------------------
// coarse_fused: blocks 0..2047 = coarse attention (v7 body, bit-identical);
// blocks 2048..2815 = fine-path pack (half-tile, 2 passes). Round-8 proven:
// 100 us, VGPR 76, pack traffic (not spill).
// ---------------------------------------------------------------------------
struct CoarseSM {
    uint32_t tls[4][640];
    float rred[2][4][16];
    float pvred[4][16][16];
    float tkv[4][16][8];
    int   tki[4][16][8];
};
union FusedSM {
    CoarseSM c;
    float tile[64][65];
};

__global__ __launch_bounds__(256)
void coarse_fused(const float* __restrict__ qc,
                  const uint4* __restrict__ KP1, const uint4* __restrict__ KP3,
                  const uint4* __restrict__ VP1,
                  float* __restrict__ msg0, int* __restrict__ topk_out,
                  const float* __restrict__ kf, const float* __restrict__ vf,
                  const float* __restrict__ qf,
                  uint32_t* __restrict__ packed, float* __restrict__ qT)
{
    __shared__ FusedSM sm;
    const int bid = blockIdx.x;
    const int tid = threadIdx.x;

    if (bid >= 2048){
        // ================= fine-path pack (half-tile, two passes) ==========
        const int pid = bid - 2048;
        const int pt = pid & 63, b = (pid >> 6) & 3, z = pid >> 8;  // z 0..2
        const float* src = (z == 0) ? kf : (z == 1) ? vf : qf;
        const int pos0 = pt * 64;

        #pragma unroll
        for (int half = 0; half < 2; ++half){
            #pragma unroll
            for (int it = 0; it < 4; ++it){
                int task = it * 256 + tid;           // 1024 tasks: ch 0..63 x p4 0..15
                int ch = task >> 4, p4 = task & 15;
                float4 v = *(const float4*)(src +
                    (size_t)(b * 128 + half * 64 + ch) * 4096 + pos0 + p4 * 4);
                sm.tile[p4*4+0][ch] = v.x; sm.tile[p4*4+1][ch] = v.y;
                sm.tile[p4*4+2][ch] = v.z; sm.tile[p4*4+3][ch] = v.w;
            }
            __syncthreads();

            if (z == 2){
                #pragma unroll
                for (int it = 0; it < 4; ++it){
                    int task = it * 256 + tid;       // p 0..63 x c4 0..15
                    int p = task >> 4, c4 = task & 15;
                    float4 v = make_float4(sm.tile[p][c4*4+0], sm.tile[p][c4*4+1],
                                           sm.tile[p][c4*4+2], sm.tile[p][c4*4+3]);
                    *(float4*)(qT + ((size_t)(b * 4096) + pos0 + p) * 128
                                  + half * 64 + c4 * 4) = v;
                }
            } else {
                int hq = half * 4 + (tid >> 6), y = tid & 63;  // 256 tasks
                int hql = tid >> 6;                             // local 0..3
                int pprime = ((pt >> 1) * 32 + (y >> 1)) * 4 + (pt & 1) * 2 + (y & 1);
                size_t line = (size_t)(b * 8 + hq) * 4096 + pprime;
                uint32_t dw[8];
                #pragma unroll
                for (int i = 0; i < 8; ++i){
                    uint32_t lo = f2b_bits(sm.tile[y][hql * 16 + 2 * i]);
                    uint32_t hi = f2b_bits(sm.tile[y][hql * 16 + 2 * i + 1]);
                    dw[i] = lo | (hi << 16);
                }
                uint4* dst4 = (uint4*)packed + line * 4 + z * 2;
                dst4[0] = make_uint4(dw[0], dw[1], dw[2], dw[3]);
                dst4[1] = make_uint4(dw[4], dw[5], dw[6], dw[7]);
            }
            __syncthreads();
        }
        return;
    }

    // ==================== coarse attention (v7, bit-identical) =============
    const int ltile = bid & 63;
    const int h = (bid >> 6) & 7, b = bid >> 9;
    const int bh = b * 8 + h;
    const int lane = tid & 63, wv = tid >> 6;  // wv 0..3
    const int quad = lane >> 4, col = lane & 15;
    const int lanex = lane ^ 32;
    const int lbase = ltile * 16;
    CoarseSM& C = sm.c;

    // ---- A-frags from Q (3-term bf16 split; TEMP folded in, exact pow2)
    v8s a1, a3;
    {
        int row = lbase + col;
        int dch0 = (quad & 1) * 8;
        #pragma unroll
        for (int j = 0; j < 8; ++j){
            float x = qc[(size_t)(b * 128 + h * 16 + dch0 + j) * 1024 + row] * TEMP;
            uint32_t u0 = f2b_bits(x);
            float r1 = x - b2f((u16)u0);
            uint32_t u1 = f2b_bits(r1);
            float r2 = r1 - b2f((u16)u1);
            uint32_t u2 = f2b_bits(r2);
            a1[j] = (short)(quad < 2 ? u0 : u1);
            a3[j] = (short)(quad < 2 ? u0 : u2);
        }
    }

    // ---- scores: 16 C-tiles
    const size_t fbase = (size_t)bh * 64 * 64;
    v4f sc[16];
    #pragma unroll
    for (int kt = 0; kt < 16; ++kt){
        int ktg = wv * 16 + kt;
        v8s b1 = asv8s(KP1[fbase + (size_t)ktg * 64 + lane]);
        v8s b2 = asv8s(KP1[fbase + (size_t)ktg * 64 + lanex]);  // [K1|K0]
        v8s b3 = asv8s(KP3[fbase + (size_t)ktg * 64 + lane]);
        v4f c = {0.f, 0.f, 0.f, 0.f};
        c = __builtin_amdgcn_mfma_f32_16x16x32_bf16(a1, b1, c, 0, 0, 0);
        c = __builtin_amdgcn_mfma_f32_16x16x32_bf16(a1, b2, c, 0, 0, 0);
        c = __builtin_amdgcn_mfma_f32_16x16x32_bf16(a3, b3, c, 0, 0, 0);
        sc[kt] = c;
    }

    // ---- softmax
    #pragma unroll
    for (int r = 0; r < 4; ++r){
        float m = sc[0][r];
        #pragma unroll
        for (int kt = 1; kt < 16; ++kt) m = fmaxf(m, sc[kt][r]);
        m = red16_max(m);
        if (col == 0) C.rred[0][wv][quad * 4 + r] = m;
    }
    __syncthreads();
    #pragma unroll
    for (int r = 0; r < 4; ++r){
        int row = quad * 4 + r;
        float m = fmaxf(fmaxf(C.rred[0][0][row], C.rred[0][1][row]),
                        fmaxf(C.rred[0][2][row], C.rred[0][3][row]));
        #pragma unroll
        for (int kt = 0; kt < 16; ++kt) sc[kt][r] = __expf(sc[kt][r] - m);
    }
    #pragma unroll
    for (int r = 0; r < 4; ++r){
        float s = 0.f;
        #pragma unroll
        for (int kt = 0; kt < 16; ++kt) s += sc[kt][r];
        s = red16_sum(s);
        if (col == 0) C.rred[1][wv][quad * 4 + r] = s;
    }

    // ---- PV: cvt_pk split, 2-kt batched LDS transpose
    v4f acc = {0.f, 0.f, 0.f, 0.f};
    uint32_t* tw = C.tls[wv];
    const int rdbase = col * 20 + 8 * (quad & 1);
    const uint32_t selp = (quad < 2) ? 0x05040100u : 0x07060302u;
    #pragma unroll
    for (int kb = 0; kb < 8; ++kb){
        #pragma unroll
        for (int ki = 0; ki < 2; ++ki){
            int kt = kb * 2 + ki;
            #pragma unroll
            for (int r = 0; r < 4; ++r)
                tw[ki * 320 + (quad * 4 + r) * 20 + col] = split2_pk(sc[kt][r]);
        }
        __builtin_amdgcn_s_waitcnt(0xC07F);
        #pragma unroll
        for (int ki = 0; ki < 2; ++ki){
            int kt = kb * 2 + ki;
            uint4 d0 = *(const uint4*)&tw[ki * 320 + rdbase];
            uint4 d1 = *(const uint4*)&tw[ki * 320 + rdbase + 4];
            I4S ux;
            ux.i[0] = __builtin_amdgcn_perm(d0.y, d0.x, selp);
            ux.i[1] = __builtin_amdgcn_perm(d0.w, d0.z, selp);
            ux.i[2] = __builtin_amdgcn_perm(d1.y, d1.x, selp);
            ux.i[3] = __builtin_amdgcn_perm(d1.w, d1.z, selp);
            v8s ap = ux.s;
            v8s bv1 = asv8s(VP1[fbase + (size_t)(wv * 16 + kt) * 64 + lane]);
            v8s bv2 = asv8s(VP1[fbase + (size_t)(wv * 16 + kt) * 64 + lanex]);
            acc = __builtin_amdgcn_mfma_f32_16x16x32_bf16(ap, bv1, acc, 0, 0, 0);
            acc = __builtin_amdgcn_mfma_f32_16x16x32_bf16(ap, bv2, acc, 0, 0, 0);
        }
    }
    #pragma unroll
    for (int r = 0; r < 4; ++r) C.pvred[wv][quad * 4 + r][col] = acc[r];

    // ---- top-8 (EXACT fp32 + DPP u64-key butterfly)
    #pragma unroll
    for (int r = 0; r < 4; ++r){
        int row = quad * 4 + r;
        float wval = 0.f; int widx = 0;
        #pragma unroll
        for (int rnd = 0; rnd < 8; ++rnd){
            float bv = sc[0][r]; int bk = 0;
            #pragma unroll
            for (int kt = 1; kt < 16; ++kt){
                bool g = sc[kt][r] > bv;
                bv = g ? sc[kt][r] : bv; bk = g ? kt : bk;
            }
            int bi = bk * 16 + col;
            uint64_t k = ((uint64_t)(uint32_t)__float_as_int(bv) << 32)
                       | (uint32_t)(~bi);
            k = red16_maxkey(k);
            bv = __int_as_float((int)(uint32_t)(k >> 32));
            bi = (int)(~(uint32_t)k);
            if ((bi & 15) == col){
                int ktw = bi >> 4;
                #pragma unroll
                for (int kt = 0; kt < 16; ++kt)
                    if (kt == ktw) sc[kt][r] = -1.0f;
            }
            if (col == rnd){ wval = bv; widx = wv * 256 + bi; }
        }
        if (col < 8){ C.tkv[wv][row][col] = wval; C.tki[wv][row][col] = widx; }
    }
    __syncthreads();

    // ---- msg0 write + 4-way top-k merge
    {
        int row = tid >> 4, dd = tid & 15;
        float v = C.pvred[0][row][dd] + C.pvred[1][row][dd] +
                  C.pvred[2][row][dd] + C.pvred[3][row][dd];
        float s = C.rred[1][0][row] + C.rred[1][1][row] +
                  C.rred[1][2][row] + C.rred[1][3][row];
        msg0[((size_t)((b * 1024 + lbase + row) * 8 + h)) * 16 + dd] = v / s;
    }
    if (tid < 16){
        int row = tid;
        int* tp = topk_out + (((b * 1024 + lbase + row) * 8 + h) * 8);
        int p[4] = {0, 0, 0, 0};
        #pragma unroll
        for (int rnd = 0; rnd < 8; ++rnd){
            float bv = -3.0f; int bw = 0, bi = 0x7fffffff;
            #pragma unroll
            for (int w = 0; w < 4; ++w){
                float v = C.tkv[w][row][p[w]];
                int   i = C.tki[w][row][p[w]];
                bool g = (v > bv) || (v == bv && i < bi);
                bv = g ? v : bv; bi = g ? i : bi; bw = g ? w : bw;
            }
            tp[rnd] = bi;
            p[bw]++;
        }
    }
}

// ---------------------------------------------------------------------------
// coarse_mfma standalone (doM && !doT fallback) — v7 body.
// ---------------------------------------------------------------------------
__global__ __launch_bounds__(256)
void coarse_mfma(const float* __restrict__ qc,
                 const uint4* __restrict__ KP1, const uint4* __restrict__ KP3,
                 const uint4* __restrict__ VP1,
                 float* __restrict__ msg0, int* __restrict__ topk_out)
{
    const int ltile = blockIdx.x;
    const int h = blockIdx.y, b = blockIdx.z;
    const int bh = b * 8 + h;
    const int tid = threadIdx.x, lane = tid & 63, wv = tid >> 6;
    const int quad = lane >> 4, col = lane & 15;
    const int lanex = lane ^ 32;
    const int lbase = ltile * 16;

    __shared__ CoarseSM C;

    v8s a1, a3;
    {
        int row = lbase + col;
        int dch0 = (quad & 1) * 8;
        #pragma unroll
        for (int j = 0; j < 8; ++j){
            float x = qc[(size_t)(b * 128 + h * 16 + dch0 + j) * 1024 + row] * TEMP;
            uint32_t u0 = f2b_bits(x);
            float r1 = x - b2f((u16)u0);
            uint32_t u1 = f2b_bits(r1);
            float r2 = r1 - b2f((u16)u1);
            uint32_t u2 = f2b_bits(r2);
            a1[j] = (short)(quad < 2 ? u0 : u1);
            a3[j] = (short)(quad < 2 ? u0 : u2);
        }
    }

    const size_t fbase = (size_t)bh * 64 * 64;
    v4f sc[16];
    #pragma unroll
    for (int kt = 0; kt < 16; ++kt){
        int ktg = wv * 16 + kt;
        v8s b1 = asv8s(KP1[fbase + (size_t)ktg * 64 + lane]);
        v8s b2 = asv8s(KP1[fbase + (size_t)ktg * 64 + lanex]);
        v8s b3 = asv8s(KP3[fbase + (size_t)ktg * 64 + lane]);
        v4f c = {0.f, 0.f, 0.f, 0.f};
        c = __builtin_amdgcn_mfma_f32_16x16x32_bf16(a1, b1, c, 0, 0, 0);
        c = __builtin_amdgcn_mfma_f32_16x16x32_bf16(a1, b2, c, 0, 0, 0);
        c = __builtin_amdgcn_mfma_f32_16x16x32_bf16(a3, b3, c, 0, 0, 0);
        sc[kt] = c;
    }

    #pragma unroll
    for (int r = 0; r < 4; ++r){
        float m = sc[0][r];
        #pragma unroll
        for (int kt = 1; kt < 16; ++kt) m = fmaxf(m, sc[kt][r]);
        m = red16_max(m);
        if (col == 0) C.rred[0][wv][quad * 4 + r] = m;
    }
    __syncthreads();
    #pragma unroll
    for (int r = 0; r < 4; ++r){
        int row = quad * 4 + r;
        float m = fmaxf(fmaxf(C.rred[0][0][row], C.rred[0][1][row]),
                        fmaxf(C.rred[0][2][row], C.rred[0][3][row]));
        #pragma unroll
        for (int kt = 0; kt < 16; ++kt) sc[kt][r] = __expf(sc[kt][r] - m);
    }
    #pragma unroll
    for (int r = 0; r < 4; ++r){
        float s = 0.f;
        #pragma unroll
        for (int kt = 0; kt < 16; ++kt) s += sc[kt][r];
        s = red16_sum(s);
        if (col == 0) C.rred[1][wv][quad * 4 + r] = s;
    }

    v4f acc = {0.f, 0.f, 0.f, 0.f};
    uint32_t* tw = C.tls[wv];
    const int rdbase = col * 20 + 8 * (quad & 1);
    const uint32_t selp = (quad < 2) ? 0x05040100u : 0x07060302u;
    #pragma unroll
    for (int kb = 0; kb < 8; ++kb){
        #pragma unroll
        for (int ki = 0; ki < 2; ++ki){
            int kt = kb * 2 + ki;
            #pragma unroll
            for (int r = 0; r < 4; ++r)
                tw[ki * 320 + (quad * 4 + r) * 20 + col] = split2_pk(sc[kt][r]);
        }
        __builtin_amdgcn_s_waitcnt(0xC07F);
        #pragma unroll
        for (int ki = 0; ki < 2; ++ki){
            int kt = kb * 2 + ki;
            uint4 d0 = *(const uint4*)&tw[ki * 320 + rdbase];
            uint4 d1 = *(const uint4*)&tw[ki * 320 + rdbase + 4];
            I4S ux;
            ux.i[0] = __builtin_amdgcn_perm(d0.y, d0.x, selp);
            ux.i[1] = __builtin_amdgcn_perm(d0.w, d0.z, selp);
            ux.i[2] = __builtin_amdgcn_perm(d1.y, d1.x, selp);
            ux.i[3] = __builtin_amdgcn_perm(d1.w, d1.z, selp);
            v8s ap = ux.s;
            v8s bv1 = asv8s(VP1[fbase + (size_t)(wv * 16 + kt) * 64 + lane]);
            v8s bv2 = asv8s(VP1[fbase + (size_t)(wv * 16 + kt) * 64 + lanex]);
            acc = __builtin_amdgcn_mfma_f32_16x16x32_bf16(ap, bv1, acc, 0, 0, 0);
            acc = __builtin_amdgcn_mfma_f32_16x16x32_bf16(ap, bv2, acc, 0, 0, 0);
        }
    }
    #pragma unroll
    for (int r = 0; r < 4; ++r) C.pvred[wv][quad * 4 + r][col] = acc[r];

    #pragma unroll
    for (int r = 0; r < 4; ++r){
        int row = quad * 4 + r;
        float wval = 0.f; int widx = 0;
        #pragma unroll
        for (int rnd = 0; rnd < 8; ++rnd){
            float bv = sc[0][r]; int bk = 0;
            #pragma unroll
            for (int kt = 1; kt < 16; ++kt){
                bool g = sc[kt][r] > bv;
                bv = g ? sc[kt][r] : bv; bk = g ? kt : bk;
            }
            int bi = bk * 16 + col;
            uint64_t k = ((uint64_t)(uint32_t)__float_as_int(bv) << 32)
                       | (uint32_t)(~bi);
            k = red16_maxkey(k);
            bv = __int_as_float((int)(uint32_t)(k >> 32));
            bi = (int)(~(uint32_t)k);
            if ((bi & 15) == col){
                int ktw = bi >> 4;
                #pragma unroll
                for (int kt = 0; kt < 16; ++kt)
                    if (kt == ktw) sc[kt][r] = -1.0f;
            }
            if (col == rnd){ wval = bv; widx = wv * 256 + bi; }
        }
        if (col < 8){ C.tkv[wv][row][col] = wval; C.tki[wv][row][col] = widx; }
    }
    __syncthreads();

    {
        int row = tid >> 4, dd = tid & 15;
        float v = C.pvred[0][row][dd] + C.pvred[1][row][dd] +
                  C.pvred[2][row][dd] + C.pvred[3][row][dd];
        float s = C.rred[1][0][row] + C.rred[1][1][row] +
                  C.rred[1][2][row] + C.rred[1][3][row];
        msg0[((size_t)((b * 1024 + lbase + row) * 8 + h)) * 16 + dd] = v / s;
    }
    if (tid < 16){
        int row = tid;
        int* tp = topk_out + (((b * 1024 + lbase + row) * 8 + h) * 8);
        int p[4] = {0, 0, 0, 0};
        #pragma unroll
        for (int rnd = 0; rnd < 8; ++rnd){
            float bv = -3.0f; int bw = 0, bi = 0x7fffffff;
            #pragma unroll
            for (int w = 0; w < 4; ++w){
                float v = C.tkv[w][row][p[w]];
                int   i = C.tki[w][row][p[w]];
                bool g = (v > bv) || (v == bv && i < bi);
                bv = g ? v : bv; bi = g ? i : bi; bw = g ? w : bw;
            }
            tp[rnd] = bi;
            p[bw]++;
        }
    }
}

// ---------------------------------------------------------------------------
// Coarse fallback (only if ws too small).
// ---------------------------------------------------------------------------
__global__ __launch_bounds__(512, 2)
void coarse_kernel(const float* __restrict__ qc, const float* __restrict__ kc,
                   const float* __restrict__ vc, float* __restrict__ msg0,
                   int* __restrict__ topk_out)
{
    const int ltile = blockIdx.x;
    const int h = blockIdx.y, b = blockIdx.z;
    const int tid = threadIdx.x;
    const int lane = tid & 63, wv = tid >> 6;
    const int lbase = ltile * 32;
    __shared__ float sKV[16 * 1024];
    const size_t base = (size_t)(b * 128 + h * 16) * 1024;
    {
        const float4* gK = (const float4*)(kc + base);
        float4* lK = (float4*)sKV;
        #pragma unroll
        for (int i = 0; i < 8; ++i) lK[tid + 512 * i] = gK[tid + 512 * i];
    }
    float qreg[4];
    {
        int dq = lane & 15;
        #pragma unroll
        for (int li = 0; li < 4; ++li){
            int l = lbase + wv * 4 + li;
            qreg[li] = qc[base + (size_t)dq * 1024 + l] * TEMP;
        }
    }
    __syncthreads();
    float p[4][16];
    #pragma unroll
    for (int li = 0; li < 4; ++li)
        #pragma unroll
        for (int j = 0; j < 16; ++j) p[li][j] = 0.f;
    #pragma unroll
    for (int dch = 0; dch < 16; ++dch){
        float kfv[16];
        #pragma unroll
        for (int ch = 0; ch < 4; ++ch){
            float4 kv = *(const float4*)&sKV[dch * 1024 + ch * 256 + (lane << 2)];
            kfv[ch*4+0] = kv.x; kfv[ch*4+1] = kv.y; kfv[ch*4+2] = kv.z; kfv[ch*4+3] = kv.w;
        }
        float qs[4];
        #pragma unroll
        for (int li = 0; li < 4; ++li) qs[li] = __shfl(qreg[li], dch);
        #pragma unroll
        for (int li = 0; li < 4; ++li)
            #pragma unroll
            for (int j = 0; j < 16; ++j) p[li][j] = fmaf(qs[li], kfv[j], p[li][j]);
    }
    float invs[4];
    #pragma unroll
    for (int li = 0; li < 4; ++li){
        float m = p[li][0];
        #pragma unroll
        for (int j = 1; j < 16; ++j) m = fmaxf(m, p[li][j]);
        #pragma unroll
        for (int off = 32; off > 0; off >>= 1) m = fmaxf(m, __shfl_xor(m, off));
        float s = 0.f;
        #pragma unroll
        for (int j = 0; j < 16; ++j){ p[li][j] = __expf(p[li][j] - m); s += p[li][j]; }
        #pragma unroll
        for (int off = 32; off > 0; off >>= 1) s += __shfl_xor(s, off);
        invs[li] = 1.0f / s;
    }
    __syncthreads();
    {
        const float4* gV = (const float4*)(vc + base);
        float4* lV = (float4*)sKV;
        #pragma unroll
        for (int i = 0; i < 8; ++i) lV[tid + 512 * i] = gV[tid + 512 * i];
    }
    __syncthreads();
    float outv = 0.f;
    #pragma unroll
    for (int dd = 0; dd < 16; ++dd){
        float vf2[16];
        #pragma unroll
        for (int ch = 0; ch < 4; ++ch){
            float4 vv = *(const float4*)&sKV[dd * 1024 + ch * 256 + (lane << 2)];
            vf2[ch*4+0] = vv.x; vf2[ch*4+1] = vv.y; vf2[ch*4+2] = vv.z; vf2[ch*4+3] = vv.w;
        }
        float a[4];
        #pragma unroll
        for (int li = 0; li < 4; ++li){
            float s = 0.f;
            #pragma unroll
            for (int j = 0; j < 16; ++j) s = fmaf(p[li][j], vf2[j], s);
            a[li] = s;
        }
        #pragma unroll
        for (int off = 32; off > 0; off >>= 1)
            #pragma unroll
            for (int li = 0; li < 4; ++li) a[li] += __shfl_xor(a[li], off);
        #pragma unroll
        for (int li = 0; li < 4; ++li)
            outv = (lane == li * 16 + dd) ? a[li] * invs[li] : outv;
    }
    {
        int li = lane >> 4, dd = lane & 15;
        int l = lbase + wv * 4 + li;
        msg0[(size_t)((b * 1024 + l) * 8 + h) * 16 + dd] = outv;
    }
    const int lanebase = lane << 4;
    int mytk = 0;
    for (int r = 0; r < 8; ++r){
        float bv[4]; int bi[4];
        #pragma unroll
        for (int li = 0; li < 4; ++li){
            float v0[8]; int j0[8];
            #pragma unroll
            for (int k = 0; k < 8; ++k){
                bool g = p[li][2*k+1] > p[li][2*k];
                v0[k] = g ? p[li][2*k+1] : p[li][2*k];
                j0[k] = g ? 2*k+1 : 2*k;
            }
            float v1[4]; int j1[4];
            #pragma unroll
            for (int k = 0; k < 4; ++k){
                bool g = v0[2*k+1] > v0[2*k];
                v1[k] = g ? v0[2*k+1] : v0[2*k];
                j1[k] = g ? j0[2*k+1] : j0[2*k];
            }
            float v2[2]; int j2[2];
            #pragma unroll
            for (int k = 0; k < 2; ++k){
                bool g = v1[2*k+1] > v1[2*k];
                v2[k] = g ? v1[2*k+1] : v1[2*k];
                j2[k] = g ? j1[2*k+1] : j1[2*k];
            }
            bool g3 = v2[1] > v2[0];
            bv[li] = g3 ? v2[1] : v2[0];
            bi[li] = lanebase | (g3 ? j2[1] : j2[0]);
        }
        #pragma unroll
        for (int off = 32; off > 0; off >>= 1){
            #pragma unroll
            for (int li = 0; li < 4; ++li){
                float ov = __shfl_xor(bv[li], off);
                int   oi = __shfl_xor(bi[li], off);
                bool g = (ov > bv[li]) || (ov == bv[li] && oi < bi[li]);
                bv[li] = g ? ov : bv[li];
                bi[li] = g ? oi : bi[li];
            }
        }
        #pragma unroll
        for (int li = 0; li < 4; ++li){
            #pragma unroll
            for (int j = 0; j < 16; ++j)
                p[li][j] = (bi[li] == (lanebase | j)) ? -1.0f : p[li][j];
            mytk = (lane == li * 8 + r) ? bi[li] : mytk;
        }
    }
    if (lane < 32){
        int li = lane >> 3, r = lane & 7;
        int jw = mytk & 15, lw = mytk >> 4;
        int s = ((jw >> 2) << 8) | (lw << 2) | (jw & 3);
        int l = lbase + wv * 4 + li;
        topk_out[((b * 1024 + l) * 8 + h) * 8 + r] = s;
    }
}

// ---------------------------------------------------------------------------
// Fine-path pack standalone (fallback when !doM && doT).
// ---------------------------------------------------------------------------
__global__ __launch_bounds__(256)
void pack_kernel(const float* __restrict__ kf, const float* __restrict__ vf,
                 const float* __restrict__ qf,
                 uint32_t* __restrict__ packed, float* __restrict__ qT)
{
    const int pt = blockIdx.x;
    const int b  = blockIdx.y;
    const int z  = blockIdx.z;
    const float* src = (z == 0) ? kf : (z == 1) ? vf : qf;
    const int tid = threadIdx.x;
    __shared__ float tile[64][129];
    const int pos0 = pt * 64;

    #pragma unroll
    for (int it = 0; it < 8; ++it){
        int task = it * 256 + tid;
        int ch = task >> 4, p4 = task & 15;
        float4 v = *(const float4*)(src + (size_t)(b * 128 + ch) * 4096 + pos0 + p4 * 4);
        tile[p4*4+0][ch] = v.x; tile[p4*4+1][ch] = v.y;
        tile[p4*4+2][ch] = v.z; tile[p4*4+3][ch] = v.w;
    }
    __syncthreads();

    if (z == 2){
        #pragma unroll
        for (int it = 0; it < 8; ++it){
            int task = it * 256 + tid;
            int p = task >> 5, c4 = task & 31;
            float4 v = make_float4(tile[p][c4*4+0], tile[p][c4*4+1],
                                   tile[p][c4*4+2], tile[p][c4*4+3]);
            *(float4*)(qT + ((size_t)(b * 4096) + pos0 + p) * 128 + c4 * 4) = v;
        }
    } else {
        const int x = pt;
        #pragma unroll
        for (int it = 0; it < 2; ++it){
            int task = it * 256 + tid;
            int h = task >> 6, y = task & 63;
            int pprime = ((x >> 1) * 32 + (y >> 1)) * 4 + (x & 1) * 2 + (y & 1);
            size_t line = (size_t)(b * 8 + h) * 4096 + pprime;
            uint32_t dw[8];
            #pragma unroll
            for (int i = 0; i < 8; ++i){
                uint32_t lo = f2b_bits(tile[y][h * 16 + 2 * i]);
                uint32_t hi = f2b_bits(tile[y][h * 16 + 2 * i + 1]);
                dw[i] = lo | (hi << 16);
            }
            uint4* dst4 = (uint4*)packed + line * 4 + z * 2;
            dst4[0] = make_uint4(dw[0], dw[1], dw[2], dw[3]);
            dst4[1] = make_uint4(dw[4], dw[5], dw[6], dw[7]);
        }
    }
}

// ---------------------------------------------------------------------------
// Fine level + combine v4: latency-chain shortened — (a) per-thread direct
// topk load (no tkS LDS round-trip, no first barrier), (b) msg0/wt hoisted
// to kernel start so they overlap the gather+compute. Values bit-identical
// to round 6 (loads reordered only).
// ---------------------------------------------------------------------------
__global__ __launch_bounds__(256)
void fine_kernel(const float* __restrict__ qf, const float* __restrict__ kf,
                 const float* __restrict__ vf,
                 const float* __restrict__ qTg, const uint32_t* __restrict__ packed,
                 int transposed,
                 const float* __restrict__ wt,
                 const int* __restrict__ topk_in, const float* __restrict__ msg0,
                 float* __restrict__ out)
{
    const int l0 = blockIdx.x;
    const int b  = blockIdx.y;
    const int tid = threadIdx.x;

    __shared__ uint32_t vTp[8][8][34];   // [head][ch-pair][key] packed bf16x2
    __shared__ float qT[8][4][16];
    __shared__ float pT[8][4][32];

    const int i = l0 >> 5, j = l0 & 31;
    const int hh = tid >> 5;
    const int t  = tid & 31;
    const int kk = t >> 2, cp = t & 3;
    const int dd = tid & 15;

    // ---- chain head: issue all independent global loads immediately
    const float w0 = wt[0], w1 = wt[1];
    const float m0 = msg0[(size_t)((b * 1024 + l0) * 8 + hh) * 16 + dd];
    const int s = topk_in[((b * 1024 + l0) * 8 + hh) * 8 + kk];

    float k[16];
    {
        if (transposed){
            const uint4* pk = (const uint4*)packed;
            size_t line = (size_t)(b * 8 + hh) * 4096 + s * 4 + cp;
            uint4 a0 = pk[line*4+0], a1 = pk[line*4+1];
            uint4 a2 = pk[line*4+2], a3 = pk[line*4+3];
            k[0]=bl(a0.x);  k[1]=bh(a0.x);  k[2]=bl(a0.y);  k[3]=bh(a0.y);
            k[4]=bl(a0.z);  k[5]=bh(a0.z);  k[6]=bl(a0.w);  k[7]=bh(a0.w);
            k[8]=bl(a1.x);  k[9]=bh(a1.x);  k[10]=bl(a1.y); k[11]=bh(a1.y);
            k[12]=bl(a1.z); k[13]=bh(a1.z); k[14]=bl(a1.w); k[15]=bh(a1.w);
            vTp[hh][0][t] = a2.x; vTp[hh][1][t] = a2.y;
            vTp[hh][2][t] = a2.z; vTp[hh][3][t] = a2.w;
            vTp[hh][4][t] = a3.x; vTp[hh][5][t] = a3.y;
            vTp[hh][6][t] = a3.z; vTp[hh][7][t] = a3.w;
        } else {
            int pos = (2 * (s >> 5) + (cp >> 1)) * 64 + 2 * (s & 31) + (cp & 1);
            size_t gb = (size_t)(b * 128 + hh * 16) * 4096 + pos;
            #pragma unroll
            for (int ch = 0; ch < 16; ++ch) k[ch] = kf[gb + (size_t)ch * 4096];
            #pragma unroll
            for (int c2 = 0; c2 < 8; ++c2){
                float f0 = vf[gb + (size_t)(2 * c2) * 4096];
                float f1 = vf[gb + (size_t)(2 * c2 + 1) * 4096];
                uint32_t pkv;
                asm("v_cvt_pk_bf16_f32 %0, %1, %2" : "=v"(pkv) : "v"(f0), "v"(f1));
                vTp[hh][c2][t] = pkv;
            }
        }
    }
    if (tid < 128){
        int qh = tid >> 4, aq = (tid >> 2) & 3, c4 = tid & 3;
        int qpos = (2 * i + (aq >> 1)) * 64 + 2 * j + (aq & 1);
        if (transposed){
            float4 u = *(const float4*)(qTg + ((size_t)(b * 4096) + qpos) * 128 + qh * 16 + c4 * 4);
            qT[qh][aq][c4*4+0] = u.x * TEMP;
            qT[qh][aq][c4*4+1] = u.y * TEMP;
            qT[qh][aq][c4*4+2] = u.z * TEMP;
            qT[qh][aq][c4*4+3] = u.w * TEMP;
        } else {
            #pragma unroll
            for (int c = 0; c < 4; ++c)
                qT[qh][aq][c4*4+c] =
                    qf[(size_t)(b * 128 + qh * 16 + c4 * 4 + c) * 4096 + qpos] * TEMP;
        }
    }
    __syncthreads();

    {
        float sc[4];
        #pragma unroll
        for (int q = 0; q < 4; ++q){
            const float4* qp = (const float4*)&qT[hh][q][0];
            float4 qa = qp[0], qb = qp[1], qc = qp[2], qd = qp[3];
            float s2 = 0.f;
            s2 = fmaf(qa.x, k[0],  s2); s2 = fmaf(qa.y, k[1],  s2);
            s2 = fmaf(qa.z, k[2],  s2); s2 = fmaf(qa.w, k[3],  s2);
            s2 = fmaf(qb.x, k[4],  s2); s2 = fmaf(qb.y, k[5],  s2);
            s2 = fmaf(qb.z, k[6],  s2); s2 = fmaf(qb.w, k[7],  s2);
            s2 = fmaf(qc.x, k[8],  s2); s2 = fmaf(qc.y, k[9],  s2);
            s2 = fmaf(qc.z, k[10], s2); s2 = fmaf(qc.w, k[11], s2);
            s2 = fmaf(qd.x, k[12], s2); s2 = fmaf(qd.y, k[13], s2);
            s2 = fmaf(qd.z, k[14], s2); s2 = fmaf(qd.w, k[15], s2);
            sc[q] = s2;
        }
        #pragma unroll
        for (int q = 0; q < 4; ++q){
            float m = red16_max(sc[q]);
            m = fmaxf(m, sw16(m));               // 32-lane max (exact)
            float e = __expf(sc[q] - m);
            float s2 = red16_sum(e);
            s2 += sw16(s2);                      // 32-lane sum
            pT[hh][q][t] = e / s2;
        }
    }
    __syncthreads();

    {
        float mx = fmaxf(w0, w1);
        float e0 = __expf(w0 - mx), e1 = __expf(w1 - mx);
        float w0f = e0 / (e0 + e1), w1f = e1 / (e0 + e1);

        int q0 = (tid >> 4) & 1;
        int cpair = dd >> 1;
        int sh = (dd & 1) << 4;                  // 0: low half, 16: high half
        float a0 = 0.f, a1 = 0.f;
        #pragma unroll
        for (int half = 0; half < 2; ++half){
            const float4* pAr = (const float4*)&pT[hh][q0][half * 16];
            const float4* pBr = (const float4*)&pT[hh][q0 + 2][half * 16];
            float pav[16], pbv[16];
            *(float4*)&pav[0]  = pAr[0]; *(float4*)&pav[4]  = pAr[1];
            *(float4*)&pav[8]  = pAr[2]; *(float4*)&pav[12] = pAr[3];
            *(float4*)&pbv[0]  = pBr[0]; *(float4*)&pbv[4]  = pBr[1];
            *(float4*)&pbv[8]  = pBr[2]; *(float4*)&pbv[12] = pBr[3];
            #pragma unroll
            for (int tq = 0; tq < 8; ++tq){
                int tt = half * 8 + tq;
                uint2 uu = *(const uint2*)&vTp[hh][cpair][tt * 2];
                float v0 = __uint_as_float((uu.x >> sh) << 16);
                float v1 = __uint_as_float((uu.y >> sh) << 16);
                a0 = fmaf(pav[tq*2], v0, a0); a0 = fmaf(pav[tq*2+1], v1, a0);
                a1 = fmaf(pbv[tq*2], v0, a1); a1 = fmaf(pbv[tq*2+1], v1, a1);
            }
        }
        float o0 = w0f * m0 + w1f * a0;
        float o1 = w0f * m0 + w1f * a1;
        int posA = (2 * i) * 64 + 2 * j + q0;
        int posB = (2 * i + 1) * 64 + 2 * j + q0;
        out[(size_t)((b * 4096 + posA) * 8 + hh) * 16 + dd] = o0;
        out[(size_t)((b * 4096 + posB) * 8 + hh) * 16 + dd] = o1;
    }
}

extern "C" void kernel_launch(void* const* d_in, const int* in_sizes, int n_in,
                              void* d_out, int out_size, void* d_ws, size_t ws_size,
                              hipStream_t stream)
{
    (void)in_sizes; (void)n_in; (void)out_size;

    const float* q_fine   = (const float*)d_in[0];
    const float* q_coarse = (const float*)d_in[1];
    const float* k_fine   = (const float*)d_in[2];
    const float* k_coarse = (const float*)d_in[3];
    const float* v_fine   = (const float*)d_in[4];
    const float* v_coarse = (const float*)d_in[5];
    const float* weight   = (const float*)d_in[6];

    const size_t MB = 1024 * 1024;
    float*    msg0   = (float*)d_ws;                          // 2 MB
    int*      topk   = (int*)((char*)d_ws + 2 * MB);          // 1 MB
    float*    qT     = (float*)((char*)d_ws + 3 * MB);        // 8 MB
    uint32_t* packed = (uint32_t*)((char*)d_ws + 11 * MB);    // 8 MB
    uint4*    KP1    = (uint4*)((char*)d_ws + 19 * MB);       // 2 MB
    uint4*    KP3    = (uint4*)((char*)d_ws + 21 * MB);       // 2 MB
    uint4*    VP1    = (uint4*)((char*)d_ws + 23 * MB);       // 2 MB
    const int doT = (ws_size >= 19 * MB) ? 1 : 0;
    const int doM = (ws_size >= 25 * MB) ? 1 : 0;

    if (doM){
        pack_coarse<<<dim3(32, 2, 8), dim3(256), 0, stream>>>(k_coarse, v_coarse,
                                                              KP1, KP3, VP1);
        if (doT){
            coarse_fused<<<dim3(2816), dim3(256), 0, stream>>>(
                q_coarse, KP1, KP3, VP1, msg0, topk,
                k_fine, v_fine, q_fine, packed, qT);
        } else {
            coarse_mfma<<<dim3(64, 8, 4), dim3(256), 0, stream>>>(q_coarse, KP1, KP3,
                                                                  VP1, msg0, topk);
        }
    } else {
        coarse_kernel<<<dim3(32, 8, 4), dim3(512), 0, stream>>>(q_coarse, k_coarse,
                                                                v_coarse, msg0, topk);
        if (doT){
            pack_kernel<<<dim3(64, 4, 3), dim3(256), 0, stream>>>(k_fine, v_fine, q_fine,
                                                                  packed, qT);
        }
    }

    fine_kernel<<<dim3(1024, 4), dim3(256), 0, stream>>>(q_fine, k_fine, v_fine,
                                                         qT, packed, doT,
                                                         weight, topk, msg0,
                                                         (float*)d_out);
}

// Round 10
// 183.539 us; speedup vs baseline: 1.0180x; 1.0180x over previous
//
#include <hip/hip_runtime.h>
#include <stdint.h>

#define TEMP 0.25f   // 1/sqrt(d), d=16

typedef unsigned short u16;
typedef short v8s __attribute__((ext_vector_type(8)));
typedef float v4f __attribute__((ext_vector_type(4)));

static __device__ __forceinline__ uint32_t f2b_bits(float f){
    union { float f; uint32_t i; } x; x.f = f;
    uint32_t u = x.i;
    return (u + 0x7FFFu + ((u >> 16) & 1u)) >> 16;   // RNE to bf16 (as u16)
}
static __device__ __forceinline__ float b2f(u16 u){
    union { uint32_t i; float f; } x; x.i = ((uint32_t)u) << 16; return x.f;
}
static __device__ __forceinline__ float bl(uint32_t u){
    union { uint32_t i; float f; } x; x.i = u << 16; return x.f;
}
static __device__ __forceinline__ float bh(uint32_t u){
    union { uint32_t i; float f; } x; x.i = u & 0xffff0000u; return x.f;
}
static __device__ __forceinline__ uint4 pack8(const uint32_t* e){
    return make_uint4(e[0] | (e[1] << 16), e[2] | (e[3] << 16),
                      e[4] | (e[5] << 16), e[6] | (e[7] << 16));
}
// trunc-hi + RNE-lo two-term bf16 split, packed u0|u1<<16 in ONE cvt op.
static __device__ __forceinline__ uint32_t split2_pk(float x){
    float hi = __uint_as_float(__float_as_uint(x) & 0xffff0000u);
    float lo = x - hi;                       // exact
    uint32_t pk;
    asm("v_cvt_pk_bf16_f32 %0, %1, %2" : "=v"(pk) : "v"(hi), "v"(lo));
    return pk;                                // lo16=trunc(x), hi16=RNE(resid)
}
union U8S { uint4 u; v8s s; };
union I4S { int i[4]; v8s s; };
static __device__ __forceinline__ v8s asv8s(uint4 u){ U8S x; x.u = u; return x.s; }

// ---- DPP helpers: full 16-lane (row) reductions, no DS-pipe traffic.
template<int C>
static __device__ __forceinline__ float dppf(float x){
    int xi = __float_as_int(x);
    return __int_as_float(__builtin_amdgcn_update_dpp(xi, xi, C, 0xf, 0xf, false));
}
static __device__ __forceinline__ float red16_max(float m){
    m = fmaxf(m, dppf<0xB1>(m));  m = fmaxf(m, dppf<0x4E>(m));
    m = fmaxf(m, dppf<0x141>(m)); m = fmaxf(m, dppf<0x140>(m));
    return m;
}
static __device__ __forceinline__ float red16_sum(float s){
    s += dppf<0xB1>(s);  s += dppf<0x4E>(s);
    s += dppf<0x141>(s); s += dppf<0x140>(s);
    return s;
}
static __device__ __forceinline__ float sw16(float x){
    return __int_as_float(__builtin_amdgcn_ds_swizzle(__float_as_int(x), 0x401F));
}
template<int C>
static __device__ __forceinline__ uint64_t dppmax64(uint64_t k){
    int hi = (int)(uint32_t)(k >> 32), lo = (int)(uint32_t)k;
    uint32_t oh = (uint32_t)__builtin_amdgcn_update_dpp(hi, hi, C, 0xf, 0xf, false);
    uint32_t ol = (uint32_t)__builtin_amdgcn_update_dpp(lo, lo, C, 0xf, 0xf, false);
    uint64_t ok = ((uint64_t)oh << 32) | ol;
    return ok > k ? ok : k;
}
static __device__ __forceinline__ uint64_t red16_maxkey(uint64_t k){
    k = dppmax64<0xB1>(k);  k = dppmax64<0x4E>(k);
    k = dppmax64<0x141>(k); k = dppmax64<0x140>(k);
    return k;
}
// Exact 16-way max via max3-fusable tree (values finite, no NaN):
// same value as sequential strict-> scan; index recovered as SMALLEST kt
// matching (descending overwrite) == first-achiever of the old scan.
#define SCAN16_MAX(SCV, BV, BK)                                              \
    {                                                                        \
        float t0 = fmaxf(fmaxf(SCV(0),  SCV(1)),  SCV(2));                   \
        float t1 = fmaxf(fmaxf(SCV(3),  SCV(4)),  SCV(5));                   \
        float t2 = fmaxf(fmaxf(SCV(6),  SCV(7)),  SCV(8));                   \
        float t3 = fmaxf(fmaxf(SCV(9),  SCV(10)), SCV(11));                  \
        float t4 = fmaxf(fmaxf(SCV(12), SCV(13)), SCV(14));                  \
        BV = fmaxf(fmaxf(fmaxf(t0, t1), t2), fmaxf(fmaxf(t3, t4), SCV(15))); \
        BK = 15;                                                             \
        _Pragma("unroll")                                                    \
        for (int kt_ = 14; kt_ >= 0; --kt_)                                  \
            BK = (SCV(kt_) == BV) ? kt_ : BK;                                \
    }

// ---------------------------------------------------------------------------
// pack_coarse: K -> KP1=[K0|K1], KP3=[K2|K0]; V -> VP1=[V0|V1].
// ---------------------------------------------------------------------------
__global__ __launch_bounds__(256)
void pack_coarse(const float* __restrict__ kc, const float* __restrict__ vc,
                 uint4* __restrict__ KP1, uint4* __restrict__ KP3,
                 uint4* __restrict__ VP1)
{
    const int bh = blockIdx.x;        // 0..31
    const int kv = blockIdx.y;        // 0:K 1:V
    const int z  = blockIdx.z;        // 0..7 (8 kt each)
    const int b = bh >> 3, h = bh & 7;
    const int tid = threadIdx.x;
    const size_t sbase = (size_t)(b * 128 + h * 16) * 1024;
    const size_t fbase = (size_t)bh * 64 * 64;

    #pragma unroll
    for (int it = 0; it < 2; ++it){
        int task = it * 256 + tid;
        int kt = z * 8 + (task >> 6), ln = task & 63;
        int quad = ln >> 4, col = ln & 15;
        if (kv == 0){
            uint32_t e1[8], e3[8];
            #pragma unroll
            for (int j = 0; j < 8; ++j){
                int dch = (quad & 1) * 8 + j;
                float x = kc[sbase + (size_t)dch * 1024 + kt * 16 + col];
                uint32_t u0 = f2b_bits(x);
                float r1 = x - b2f((u16)u0);
                uint32_t u1 = f2b_bits(r1);
                float r2 = r1 - b2f((u16)u1);
                uint32_t u2 = f2b_bits(r2);
                e1[j] = (quad < 2) ? u0 : u1;
                e3[j] = (quad < 2) ? u2 : u0;
            }
            KP1[fbase + kt * 64 + ln] = pack8(e1);
            KP3[fbase + kt * 64 + ln] = pack8(e3);
        } else {
            uint32_t e[8];
            #pragma unroll
            for (int j = 0; j < 8; ++j){
                int key = kt * 16 + (quad & 1) * 8 + j;
                float x = vc[sbase + (size_t)col * 1024 + key];
                uint32_t pk = split2_pk(x);          // (trunc, RNE) packed
                e[j] = (quad < 2) ? (pk & 0xffffu) : (pk >> 16);
            }
            VP1[fbase + kt * 64 + ln] = pack8(e);
        }
    }
}

// ---------------------------------------------------------------------------
// coarse_fused: blocks 0..2047 = coarse attention; 2048..2815 = fine pack.
// Round-8 proven (100 us, VGPR 76). This round: max3-tree scan in top-8
// (bit-identical selection, ~5 fewer VALU ops per round).
// ---------------------------------------------------------------------------
struct CoarseSM {
    uint32_t tls[4][640];
    float rred[2][4][16];
    float pvred[4][16][16];
    float tkv[4][16][8];
    int   tki[4][16][8];
};
union FusedSM {
    CoarseSM c;
    float tile[64][65];
};

__global__ __launch_bounds__(256)
void coarse_fused(const float* __restrict__ qc,
                  const uint4* __restrict__ KP1, const uint4* __restrict__ KP3,
                  const uint4* __restrict__ VP1,
                  float* __restrict__ msg0, int* __restrict__ topk_out,
                  const float* __restrict__ kf, const float* __restrict__ vf,
                  const float* __restrict__ qf,
                  uint32_t* __restrict__ packed, float* __restrict__ qT)
{
    __shared__ FusedSM sm;
    const int bid = blockIdx.x;
    const int tid = threadIdx.x;

    if (bid >= 2048){
        // ================= fine-path pack (half-tile, two passes) ==========
        const int pid = bid - 2048;
        const int pt = pid & 63, b = (pid >> 6) & 3, z = pid >> 8;  // z 0..2
        const float* src = (z == 0) ? kf : (z == 1) ? vf : qf;
        const int pos0 = pt * 64;

        #pragma unroll
        for (int half = 0; half < 2; ++half){
            #pragma unroll
            for (int it = 0; it < 4; ++it){
                int task = it * 256 + tid;           // 1024 tasks: ch 0..63 x p4 0..15
                int ch = task >> 4, p4 = task & 15;
                float4 v = *(const float4*)(src +
                    (size_t)(b * 128 + half * 64 + ch) * 4096 + pos0 + p4 * 4);
                sm.tile[p4*4+0][ch] = v.x; sm.tile[p4*4+1][ch] = v.y;
                sm.tile[p4*4+2][ch] = v.z; sm.tile[p4*4+3][ch] = v.w;
            }
            __syncthreads();

            if (z == 2){
                #pragma unroll
                for (int it = 0; it < 4; ++it){
                    int task = it * 256 + tid;       // p 0..63 x c4 0..15
                    int p = task >> 4, c4 = task & 15;
                    float4 v = make_float4(sm.tile[p][c4*4+0], sm.tile[p][c4*4+1],
                                           sm.tile[p][c4*4+2], sm.tile[p][c4*4+3]);
                    *(float4*)(qT + ((size_t)(b * 4096) + pos0 + p) * 128
                                  + half * 64 + c4 * 4) = v;
                }
            } else {
                int hq = half * 4 + (tid >> 6), y = tid & 63;  // 256 tasks
                int hql = tid >> 6;                             // local 0..3
                int pprime = ((pt >> 1) * 32 + (y >> 1)) * 4 + (pt & 1) * 2 + (y & 1);
                size_t line = (size_t)(b * 8 + hq) * 4096 + pprime;
                uint32_t dw[8];
                #pragma unroll
                for (int i = 0; i < 8; ++i){
                    uint32_t lo = f2b_bits(sm.tile[y][hql * 16 + 2 * i]);
                    uint32_t hi = f2b_bits(sm.tile[y][hql * 16 + 2 * i + 1]);
                    dw[i] = lo | (hi << 16);
                }
                uint4* dst4 = (uint4*)packed + line * 4 + z * 2;
                dst4[0] = make_uint4(dw[0], dw[1], dw[2], dw[3]);
                dst4[1] = make_uint4(dw[4], dw[5], dw[6], dw[7]);
            }
            __syncthreads();
        }
        return;
    }

    // ==================== coarse attention =============
    const int ltile = bid & 63;
    const int h = (bid >> 6) & 7, b = bid >> 9;
    const int bh = b * 8 + h;
    const int lane = tid & 63, wv = tid >> 6;  // wv 0..3
    const int quad = lane >> 4, col = lane & 15;
    const int lanex = lane ^ 32;
    const int lbase = ltile * 16;
    CoarseSM& C = sm.c;

    // ---- A-frags from Q (3-term bf16 split; TEMP folded in, exact pow2)
    v8s a1, a3;
    {
        int row = lbase + col;
        int dch0 = (quad & 1) * 8;
        #pragma unroll
        for (int j = 0; j < 8; ++j){
            float x = qc[(size_t)(b * 128 + h * 16 + dch0 + j) * 1024 + row] * TEMP;
            uint32_t u0 = f2b_bits(x);
            float r1 = x - b2f((u16)u0);
            uint32_t u1 = f2b_bits(r1);
            float r2 = r1 - b2f((u16)u1);
            uint32_t u2 = f2b_bits(r2);
            a1[j] = (short)(quad < 2 ? u0 : u1);
            a3[j] = (short)(quad < 2 ? u0 : u2);
        }
    }

    // ---- scores: 16 C-tiles
    const size_t fbase = (size_t)bh * 64 * 64;
    v4f sc[16];
    #pragma unroll
    for (int kt = 0; kt < 16; ++kt){
        int ktg = wv * 16 + kt;
        v8s b1 = asv8s(KP1[fbase + (size_t)ktg * 64 + lane]);
        v8s b2 = asv8s(KP1[fbase + (size_t)ktg * 64 + lanex]);  // [K1|K0]
        v8s b3 = asv8s(KP3[fbase + (size_t)ktg * 64 + lane]);
        v4f c = {0.f, 0.f, 0.f, 0.f};
        c = __builtin_amdgcn_mfma_f32_16x16x32_bf16(a1, b1, c, 0, 0, 0);
        c = __builtin_amdgcn_mfma_f32_16x16x32_bf16(a1, b2, c, 0, 0, 0);
        c = __builtin_amdgcn_mfma_f32_16x16x32_bf16(a3, b3, c, 0, 0, 0);
        sc[kt] = c;
    }

    // ---- softmax
    #pragma unroll
    for (int r = 0; r < 4; ++r){
        float m = sc[0][r];
        #pragma unroll
        for (int kt = 1; kt < 16; ++kt) m = fmaxf(m, sc[kt][r]);
        m = red16_max(m);
        if (col == 0) C.rred[0][wv][quad * 4 + r] = m;
    }
    __syncthreads();
    #pragma unroll
    for (int r = 0; r < 4; ++r){
        int row = quad * 4 + r;
        float m = fmaxf(fmaxf(C.rred[0][0][row], C.rred[0][1][row]),
                        fmaxf(C.rred[0][2][row], C.rred[0][3][row]));
        #pragma unroll
        for (int kt = 0; kt < 16; ++kt) sc[kt][r] = __expf(sc[kt][r] - m);
    }
    #pragma unroll
    for (int r = 0; r < 4; ++r){
        float s = 0.f;
        #pragma unroll
        for (int kt = 0; kt < 16; ++kt) s += sc[kt][r];
        s = red16_sum(s);
        if (col == 0) C.rred[1][wv][quad * 4 + r] = s;
    }

    // ---- PV: cvt_pk split, 2-kt batched LDS transpose
    v4f acc = {0.f, 0.f, 0.f, 0.f};
    uint32_t* tw = C.tls[wv];
    const int rdbase = col * 20 + 8 * (quad & 1);
    const uint32_t selp = (quad < 2) ? 0x05040100u : 0x07060302u;
    #pragma unroll
    for (int kb = 0; kb < 8; ++kb){
        #pragma unroll
        for (int ki = 0; ki < 2; ++ki){
            int kt = kb * 2 + ki;
            #pragma unroll
            for (int r = 0; r < 4; ++r)
                tw[ki * 320 + (quad * 4 + r) * 20 + col] = split2_pk(sc[kt][r]);
        }
        __builtin_amdgcn_s_waitcnt(0xC07F);
        #pragma unroll
        for (int ki = 0; ki < 2; ++ki){
            int kt = kb * 2 + ki;
            uint4 d0 = *(const uint4*)&tw[ki * 320 + rdbase];
            uint4 d1 = *(const uint4*)&tw[ki * 320 + rdbase + 4];
            I4S ux;
            ux.i[0] = __builtin_amdgcn_perm(d0.y, d0.x, selp);
            ux.i[1] = __builtin_amdgcn_perm(d0.w, d0.z, selp);
            ux.i[2] = __builtin_amdgcn_perm(d1.y, d1.x, selp);
            ux.i[3] = __builtin_amdgcn_perm(d1.w, d1.z, selp);
            v8s ap = ux.s;
            v8s bv1 = asv8s(VP1[fbase + (size_t)(wv * 16 + kt) * 64 + lane]);
            v8s bv2 = asv8s(VP1[fbase + (size_t)(wv * 16 + kt) * 64 + lanex]);
            acc = __builtin_amdgcn_mfma_f32_16x16x32_bf16(ap, bv1, acc, 0, 0, 0);
            acc = __builtin_amdgcn_mfma_f32_16x16x32_bf16(ap, bv2, acc, 0, 0, 0);
        }
    }
    #pragma unroll
    for (int r = 0; r < 4; ++r) C.pvred[wv][quad * 4 + r][col] = acc[r];

    // ---- top-8 (EXACT fp32, max3-tree scan + DPP u64-key butterfly)
    #pragma unroll
    for (int r = 0; r < 4; ++r){
        int row = quad * 4 + r;
        float wval = 0.f; int widx = 0;
        #pragma unroll
        for (int rnd = 0; rnd < 8; ++rnd){
            float bv; int bk;
            #define SCV(K) sc[K][r]
            SCAN16_MAX(SCV, bv, bk)
            #undef SCV
            int bi = bk * 16 + col;
            uint64_t k = ((uint64_t)(uint32_t)__float_as_int(bv) << 32)
                       | (uint32_t)(~bi);
            k = red16_maxkey(k);
            bv = __int_as_float((int)(uint32_t)(k >> 32));
            bi = (int)(~(uint32_t)k);
            if ((bi & 15) == col){
                int ktw = bi >> 4;
                #pragma unroll
                for (int kt = 0; kt < 16; ++kt)
                    if (kt == ktw) sc[kt][r] = -1.0f;
            }
            if (col == rnd){ wval = bv; widx = wv * 256 + bi; }
        }
        if (col < 8){ C.tkv[wv][row][col] = wval; C.tki[wv][row][col] = widx; }
    }
    __syncthreads();

    // ---- msg0 write + 4-way top-k merge
    {
        int row = tid >> 4, dd = tid & 15;
        float v = C.pvred[0][row][dd] + C.pvred[1][row][dd] +
                  C.pvred[2][row][dd] + C.pvred[3][row][dd];
        float s = C.rred[1][0][row] + C.rred[1][1][row] +
                  C.rred[1][2][row] + C.rred[1][3][row];
        msg0[((size_t)((b * 1024 + lbase + row) * 8 + h)) * 16 + dd] = v / s;
    }
    if (tid < 16){
        int row = tid;
        int* tp = topk_out + (((b * 1024 + lbase + row) * 8 + h) * 8);
        int p[4] = {0, 0, 0, 0};
        #pragma unroll
        for (int rnd = 0; rnd < 8; ++rnd){
            float bv = -3.0f; int bw = 0, bi = 0x7fffffff;
            #pragma unroll
            for (int w = 0; w < 4; ++w){
                float v = C.tkv[w][row][p[w]];
                int   i = C.tki[w][row][p[w]];
                bool g = (v > bv) || (v == bv && i < bi);
                bv = g ? v : bv; bi = g ? i : bi; bw = g ? w : bw;
            }
            tp[rnd] = bi;
            p[bw]++;
        }
    }
}

// ---------------------------------------------------------------------------
// coarse_mfma standalone (doM && !doT fallback) — same top-8 update.
// ---------------------------------------------------------------------------
__global__ __launch_bounds__(256)
void coarse_mfma(const float* __restrict__ qc,
                 const uint4* __restrict__ KP1, const uint4* __restrict__ KP3,
                 const uint4* __restrict__ VP1,
                 float* __restrict__ msg0, int* __restrict__ topk_out)
{
    const int ltile = blockIdx.x;
    const int h = blockIdx.y, b = blockIdx.z;
    const int bh = b * 8 + h;
    const int tid = threadIdx.x, lane = tid & 63, wv = tid >> 6;
    const int quad = lane >> 4, col = lane & 15;
    const int lanex = lane ^ 32;
    const int lbase = ltile * 16;

    __shared__ CoarseSM C;

    v8s a1, a3;
    {
        int row = lbase + col;
        int dch0 = (quad & 1) * 8;
        #pragma unroll
        for (int j = 0; j < 8; ++j){
            float x = qc[(size_t)(b * 128 + h * 16 + dch0 + j) * 1024 + row] * TEMP;
            uint32_t u0 = f2b_bits(x);
            float r1 = x - b2f((u16)u0);
            uint32_t u1 = f2b_bits(r1);
            float r2 = r1 - b2f((u16)u1);
            uint32_t u2 = f2b_bits(r2);
            a1[j] = (short)(quad < 2 ? u0 : u1);
            a3[j] = (short)(quad < 2 ? u0 : u2);
        }
    }

    const size_t fbase = (size_t)bh * 64 * 64;
    v4f sc[16];
    #pragma unroll
    for (int kt = 0; kt < 16; ++kt){
        int ktg = wv * 16 + kt;
        v8s b1 = asv8s(KP1[fbase + (size_t)ktg * 64 + lane]);
        v8s b2 = asv8s(KP1[fbase + (size_t)ktg * 64 + lanex]);
        v8s b3 = asv8s(KP3[fbase + (size_t)ktg * 64 + lane]);
        v4f c = {0.f, 0.f, 0.f, 0.f};
        c = __builtin_amdgcn_mfma_f32_16x16x32_bf16(a1, b1, c, 0, 0, 0);
        c = __builtin_amdgcn_mfma_f32_16x16x32_bf16(a1, b2, c, 0, 0, 0);
        c = __builtin_amdgcn_mfma_f32_16x16x32_bf16(a3, b3, c, 0, 0, 0);
        sc[kt] = c;
    }

    #pragma unroll
    for (int r = 0; r < 4; ++r){
        float m = sc[0][r];
        #pragma unroll
        for (int kt = 1; kt < 16; ++kt) m = fmaxf(m, sc[kt][r]);
        m = red16_max(m);
        if (col == 0) C.rred[0][wv][quad * 4 + r] = m;
    }
    __syncthreads();
    #pragma unroll
    for (int r = 0; r < 4; ++r){
        int row = quad * 4 + r;
        float m = fmaxf(fmaxf(C.rred[0][0][row], C.rred[0][1][row]),
                        fmaxf(C.rred[0][2][row], C.rred[0][3][row]));
        #pragma unroll
        for (int kt = 0; kt < 16; ++kt) sc[kt][r] = __expf(sc[kt][r] - m);
    }
    #pragma unroll
    for (int r = 0; r < 4; ++r){
        float s = 0.f;
        #pragma unroll
        for (int kt = 0; kt < 16; ++kt) s += sc[kt][r];
        s = red16_sum(s);
        if (col == 0) C.rred[1][wv][quad * 4 + r] = s;
    }

    v4f acc = {0.f, 0.f, 0.f, 0.f};
    uint32_t* tw = C.tls[wv];
    const int rdbase = col * 20 + 8 * (quad & 1);
    const uint32_t selp = (quad < 2) ? 0x05040100u : 0x07060302u;
    #pragma unroll
    for (int kb = 0; kb < 8; ++kb){
        #pragma unroll
        for (int ki = 0; ki < 2; ++ki){
            int kt = kb * 2 + ki;
            #pragma unroll
            for (int r = 0; r < 4; ++r)
                tw[ki * 320 + (quad * 4 + r) * 20 + col] = split2_pk(sc[kt][r]);
        }
        __builtin_amdgcn_s_waitcnt(0xC07F);
        #pragma unroll
        for (int ki = 0; ki < 2; ++ki){
            int kt = kb * 2 + ki;
            uint4 d0 = *(const uint4*)&tw[ki * 320 + rdbase];
            uint4 d1 = *(const uint4*)&tw[ki * 320 + rdbase + 4];
            I4S ux;
            ux.i[0] = __builtin_amdgcn_perm(d0.y, d0.x, selp);
            ux.i[1] = __builtin_amdgcn_perm(d0.w, d0.z, selp);
            ux.i[2] = __builtin_amdgcn_perm(d1.y, d1.x, selp);
            ux.i[3] = __builtin_amdgcn_perm(d1.w, d1.z, selp);
            v8s ap = ux.s;
            v8s bv1 = asv8s(VP1[fbase + (size_t)(wv * 16 + kt) * 64 + lane]);
            v8s bv2 = asv8s(VP1[fbase + (size_t)(wv * 16 + kt) * 64 + lanex]);
            acc = __builtin_amdgcn_mfma_f32_16x16x32_bf16(ap, bv1, acc, 0, 0, 0);
            acc = __builtin_amdgcn_mfma_f32_16x16x32_bf16(ap, bv2, acc, 0, 0, 0);
        }
    }
    #pragma unroll
    for (int r = 0; r < 4; ++r) C.pvred[wv][quad * 4 + r][col] = acc[r];

    #pragma unroll
    for (int r = 0; r < 4; ++r){
        int row = quad * 4 + r;
        float wval = 0.f; int widx = 0;
        #pragma unroll
        for (int rnd = 0; rnd < 8; ++rnd){
            float bv; int bk;
            #define SCV(K) sc[K][r]
            SCAN16_MAX(SCV, bv, bk)
            #undef SCV
            int bi = bk * 16 + col;
            uint64_t k = ((uint64_t)(uint32_t)__float_as_int(bv) << 32)
                       | (uint32_t)(~bi);
            k = red16_maxkey(k);
            bv = __int_as_float((int)(uint32_t)(k >> 32));
            bi = (int)(~(uint32_t)k);
            if ((bi & 15) == col){
                int ktw = bi >> 4;
                #pragma unroll
                for (int kt = 0; kt < 16; ++kt)
                    if (kt == ktw) sc[kt][r] = -1.0f;
            }
            if (col == rnd){ wval = bv; widx = wv * 256 + bi; }
        }
        if (col < 8){ C.tkv[wv][row][col] = wval; C.tki[wv][row][col] = widx; }
    }
    __syncthreads();

    {
        int row = tid >> 4, dd = tid & 15;
        float v = C.pvred[0][row][dd] + C.pvred[1][row][dd] +
                  C.pvred[2][row][dd] + C.pvred[3][row][dd];
        float s = C.rred[1][0][row] + C.rred[1][1][row] +
                  C.rred[1][2][row] + C.rred[1][3][row];
        msg0[((size_t)((b * 1024 + lbase + row) * 8 + h)) * 16 + dd] = v / s;
    }
    if (tid < 16){
        int row = tid;
        int* tp = topk_out + (((b * 1024 + lbase + row) * 8 + h) * 8);
        int p[4] = {0, 0, 0, 0};
        #pragma unroll
        for (int rnd = 0; rnd < 8; ++rnd){
            float bv = -3.0f; int bw = 0, bi = 0x7fffffff;
            #pragma unroll
            for (int w = 0; w < 4; ++w){
                float v = C.tkv[w][row][p[w]];
                int   i = C.tki[w][row][p[w]];
                bool g = (v > bv) || (v == bv && i < bi);
                bv = g ? v : bv; bi = g ? i : bi; bw = g ? w : bw;
            }
            tp[rnd] = bi;
            p[bw]++;
        }
    }
}

// ---------------------------------------------------------------------------
// Coarse fallback (only if ws too small).
// ---------------------------------------------------------------------------
__global__ __launch_bounds__(512, 2)
void coarse_kernel(const float* __restrict__ qc, const float* __restrict__ kc,
                   const float* __restrict__ vc, float* __restrict__ msg0,
                   int* __restrict__ topk_out)
{
    const int ltile = blockIdx.x;
    const int h = blockIdx.y, b = blockIdx.z;
    const int tid = threadIdx.x;
    const int lane = tid & 63, wv = tid >> 6;
    const int lbase = ltile * 32;
    __shared__ float sKV[16 * 1024];
    const size_t base = (size_t)(b * 128 + h * 16) * 1024;
    {
        const float4* gK = (const float4*)(kc + base);
        float4* lK = (float4*)sKV;
        #pragma unroll
        for (int i = 0; i < 8; ++i) lK[tid + 512 * i] = gK[tid + 512 * i];
    }
    float qreg[4];
    {
        int dq = lane & 15;
        #pragma unroll
        for (int li = 0; li < 4; ++li){
            int l = lbase + wv * 4 + li;
            qreg[li] = qc[base + (size_t)dq * 1024 + l] * TEMP;
        }
    }
    __syncthreads();
    float p[4][16];
    #pragma unroll
    for (int li = 0; li < 4; ++li)
        #pragma unroll
        for (int j = 0; j < 16; ++j) p[li][j] = 0.f;
    #pragma unroll
    for (int dch = 0; dch < 16; ++dch){
        float kfv[16];
        #pragma unroll
        for (int ch = 0; ch < 4; ++ch){
            float4 kv = *(const float4*)&sKV[dch * 1024 + ch * 256 + (lane << 2)];
            kfv[ch*4+0] = kv.x; kfv[ch*4+1] = kv.y; kfv[ch*4+2] = kv.z; kfv[ch*4+3] = kv.w;
        }
        float qs[4];
        #pragma unroll
        for (int li = 0; li < 4; ++li) qs[li] = __shfl(qreg[li], dch);
        #pragma unroll
        for (int li = 0; li < 4; ++li)
            #pragma unroll
            for (int j = 0; j < 16; ++j) p[li][j] = fmaf(qs[li], kfv[j], p[li][j]);
    }
    float invs[4];
    #pragma unroll
    for (int li = 0; li < 4; ++li){
        float m = p[li][0];
        #pragma unroll
        for (int j = 1; j < 16; ++j) m = fmaxf(m, p[li][j]);
        #pragma unroll
        for (int off = 32; off > 0; off >>= 1) m = fmaxf(m, __shfl_xor(m, off));
        float s = 0.f;
        #pragma unroll
        for (int j = 0; j < 16; ++j){ p[li][j] = __expf(p[li][j] - m); s += p[li][j]; }
        #pragma unroll
        for (int off = 32; off > 0; off >>= 1) s += __shfl_xor(s, off);
        invs[li] = 1.0f / s;
    }
    __syncthreads();
    {
        const float4* gV = (const float4*)(vc + base);
        float4* lV = (float4*)sKV;
        #pragma unroll
        for (int i = 0; i < 8; ++i) lV[tid + 512 * i] = gV[tid + 512 * i];
    }
    __syncthreads();
    float outv = 0.f;
    #pragma unroll
    for (int dd = 0; dd < 16; ++dd){
        float vf2[16];
        #pragma unroll
        for (int ch = 0; ch < 4; ++ch){
            float4 vv = *(const float4*)&sKV[dd * 1024 + ch * 256 + (lane << 2)];
            vf2[ch*4+0] = vv.x; vf2[ch*4+1] = vv.y; vf2[ch*4+2] = vv.z; vf2[ch*4+3] = vv.w;
        }
        float a[4];
        #pragma unroll
        for (int li = 0; li < 4; ++li){
            float s = 0.f;
            #pragma unroll
            for (int j = 0; j < 16; ++j) s = fmaf(p[li][j], vf2[j], s);
            a[li] = s;
        }
        #pragma unroll
        for (int off = 32; off > 0; off >>= 1)
            #pragma unroll
            for (int li = 0; li < 4; ++li) a[li] += __shfl_xor(a[li], off);
        #pragma unroll
        for (int li = 0; li < 4; ++li)
            outv = (lane == li * 16 + dd) ? a[li] * invs[li] : outv;
    }
    {
        int li = lane >> 4, dd = lane & 15;
        int l = lbase + wv * 4 + li;
        msg0[(size_t)((b * 1024 + l) * 8 + h) * 16 + dd] = outv;
    }
    const int lanebase = lane << 4;
    int mytk = 0;
    for (int r = 0; r < 8; ++r){
        float bv[4]; int bi[4];
        #pragma unroll
        for (int li = 0; li < 4; ++li){
            float v0[8]; int j0[8];
            #pragma unroll
            for (int k = 0; k < 8; ++k){
                bool g = p[li][2*k+1] > p[li][2*k];
                v0[k] = g ? p[li][2*k+1] : p[li][2*k];
                j0[k] = g ? 2*k+1 : 2*k;
            }
            float v1[4]; int j1[4];
            #pragma unroll
            for (int k = 0; k < 4; ++k){
                bool g = v0[2*k+1] > v0[2*k];
                v1[k] = g ? v0[2*k+1] : v0[2*k];
                j1[k] = g ? j0[2*k+1] : j0[2*k];
            }
            float v2[2]; int j2[2];
            #pragma unroll
            for (int k = 0; k < 2; ++k){
                bool g = v1[2*k+1] > v1[2*k];
                v2[k] = g ? v1[2*k+1] : v1[2*k];
                j2[k] = g ? j1[2*k+1] : j1[2*k];
            }
            bool g3 = v2[1] > v2[0];
            bv[li] = g3 ? v2[1] : v2[0];
            bi[li] = lanebase | (g3 ? j2[1] : j2[0]);
        }
        #pragma unroll
        for (int off = 32; off > 0; off >>= 1){
            #pragma unroll
            for (int li = 0; li < 4; ++li){
                float ov = __shfl_xor(bv[li], off);
                int   oi = __shfl_xor(bi[li], off);
                bool g = (ov > bv[li]) || (ov == bv[li] && oi < bi[li]);
                bv[li] = g ? ov : bv[li];
                bi[li] = g ? oi : bi[li];
            }
        }
        #pragma unroll
        for (int li = 0; li < 4; ++li){
            #pragma unroll
            for (int j = 0; j < 16; ++j)
                p[li][j] = (bi[li] == (lanebase | j)) ? -1.0f : p[li][j];
            mytk = (lane == li * 8 + r) ? bi[li] : mytk;
        }
    }
    if (lane < 32){
        int li = lane >> 3, r = lane & 7;
        int jw = mytk & 15, lw = mytk >> 4;
        int s = ((jw >> 2) << 8) | (lw << 2) | (jw & 3);
        int l = lbase + wv * 4 + li;
        topk_out[((b * 1024 + l) * 8 + h) * 8 + r] = s;
    }
}

// ---------------------------------------------------------------------------
// Fine-path pack standalone (fallback when !doM && doT).
// ---------------------------------------------------------------------------
__global__ __launch_bounds__(256)
void pack_kernel(const float* __restrict__ kf, const float* __restrict__ vf,
                 const float* __restrict__ qf,
                 uint32_t* __restrict__ packed, float* __restrict__ qT)
{
    const int pt = blockIdx.x;
    const int b  = blockIdx.y;
    const int z  = blockIdx.z;
    const float* src = (z == 0) ? kf : (z == 1) ? vf : qf;
    const int tid = threadIdx.x;
    __shared__ float tile[64][129];
    const int pos0 = pt * 64;

    #pragma unroll
    for (int it = 0; it < 8; ++it){
        int task = it * 256 + tid;
        int ch = task >> 4, p4 = task & 15;
        float4 v = *(const float4*)(src + (size_t)(b * 128 + ch) * 4096 + pos0 + p4 * 4);
        tile[p4*4+0][ch] = v.x; tile[p4*4+1][ch] = v.y;
        tile[p4*4+2][ch] = v.z; tile[p4*4+3][ch] = v.w;
    }
    __syncthreads();

    if (z == 2){
        #pragma unroll
        for (int it = 0; it < 8; ++it){
            int task = it * 256 + tid;
            int p = task >> 5, c4 = task & 31;
            float4 v = make_float4(tile[p][c4*4+0], tile[p][c4*4+1],
                                   tile[p][c4*4+2], tile[p][c4*4+3]);
            *(float4*)(qT + ((size_t)(b * 4096) + pos0 + p) * 128 + c4 * 4) = v;
        }
    } else {
        const int x = pt;
        #pragma unroll
        for (int it = 0; it < 2; ++it){
            int task = it * 256 + tid;
            int h = task >> 6, y = task & 63;
            int pprime = ((x >> 1) * 32 + (y >> 1)) * 4 + (x & 1) * 2 + (y & 1);
            size_t line = (size_t)(b * 8 + h) * 4096 + pprime;
            uint32_t dw[8];
            #pragma unroll
            for (int i = 0; i < 8; ++i){
                uint32_t lo = f2b_bits(tile[y][h * 16 + 2 * i]);
                uint32_t hi = f2b_bits(tile[y][h * 16 + 2 * i + 1]);
                dw[i] = lo | (hi << 16);
            }
            uint4* dst4 = (uint4*)packed + line * 4 + z * 2;
            dst4[0] = make_uint4(dw[0], dw[1], dw[2], dw[3]);
            dst4[1] = make_uint4(dw[4], dw[5], dw[6], dw[7]);
        }
    }
}

// ---------------------------------------------------------------------------
// Fine level + combine v5: hoisted loads (r8), direct float2 pT reads
// (lower VGPR pressure; accumulation order identical), s_setprio(1) around
// the QK and PV FMA clusters (scheduler hint only — values unchanged).
// ---------------------------------------------------------------------------
__global__ __launch_bounds__(256)
void fine_kernel(const float* __restrict__ qf, const float* __restrict__ kf,
                 const float* __restrict__ vf,
                 const float* __restrict__ qTg, const uint32_t* __restrict__ packed,
                 int transposed,
                 const float* __restrict__ wt,
                 const int* __restrict__ topk_in, const float* __restrict__ msg0,
                 float* __restrict__ out)
{
    const int l0 = blockIdx.x;
    const int b  = blockIdx.y;
    const int tid = threadIdx.x;

    __shared__ uint32_t vTp[8][8][34];   // [head][ch-pair][key] packed bf16x2
    __shared__ float qT[8][4][16];
    __shared__ float pT[8][4][32];

    const int i = l0 >> 5, j = l0 & 31;
    const int hh = tid >> 5;
    const int t  = tid & 31;
    const int kk = t >> 2, cp = t & 3;
    const int dd = tid & 15;

    // ---- chain head: issue all independent global loads immediately
    const float w0 = wt[0], w1 = wt[1];
    const float m0 = msg0[(size_t)((b * 1024 + l0) * 8 + hh) * 16 + dd];
    const int s = topk_in[((b * 1024 + l0) * 8 + hh) * 8 + kk];

    float k[16];
    {
        if (transposed){
            const uint4* pk = (const uint4*)packed;
            size_t line = (size_t)(b * 8 + hh) * 4096 + s * 4 + cp;
            uint4 a0 = pk[line*4+0], a1 = pk[line*4+1];
            uint4 a2 = pk[line*4+2], a3 = pk[line*4+3];
            k[0]=bl(a0.x);  k[1]=bh(a0.x);  k[2]=bl(a0.y);  k[3]=bh(a0.y);
            k[4]=bl(a0.z);  k[5]=bh(a0.z);  k[6]=bl(a0.w);  k[7]=bh(a0.w);
            k[8]=bl(a1.x);  k[9]=bh(a1.x);  k[10]=bl(a1.y); k[11]=bh(a1.y);
            k[12]=bl(a1.z); k[13]=bh(a1.z); k[14]=bl(a1.w); k[15]=bh(a1.w);
            vTp[hh][0][t] = a2.x; vTp[hh][1][t] = a2.y;
            vTp[hh][2][t] = a2.z; vTp[hh][3][t] = a2.w;
            vTp[hh][4][t] = a3.x; vTp[hh][5][t] = a3.y;
            vTp[hh][6][t] = a3.z; vTp[hh][7][t] = a3.w;
        } else {
            int pos = (2 * (s >> 5) + (cp >> 1)) * 64 + 2 * (s & 31) + (cp & 1);
            size_t gb = (size_t)(b * 128 + hh * 16) * 4096 + pos;
            #pragma unroll
            for (int ch = 0; ch < 16; ++ch) k[ch] = kf[gb + (size_t)ch * 4096];
            #pragma unroll
            for (int c2 = 0; c2 < 8; ++c2){
                float f0 = vf[gb + (size_t)(2 * c2) * 4096];
                float f1 = vf[gb + (size_t)(2 * c2 + 1) * 4096];
                uint32_t pkv;
                asm("v_cvt_pk_bf16_f32 %0, %1, %2" : "=v"(pkv) : "v"(f0), "v"(f1));
                vTp[hh][c2][t] = pkv;
            }
        }
    }
    if (tid < 128){
        int qh = tid >> 4, aq = (tid >> 2) & 3, c4 = tid & 3;
        int qpos = (2 * i + (aq >> 1)) * 64 + 2 * j + (aq & 1);
        if (transposed){
            float4 u = *(const float4*)(qTg + ((size_t)(b * 4096) + qpos) * 128 + qh * 16 + c4 * 4);
            qT[qh][aq][c4*4+0] = u.x * TEMP;
            qT[qh][aq][c4*4+1] = u.y * TEMP;
            qT[qh][aq][c4*4+2] = u.z * TEMP;
            qT[qh][aq][c4*4+3] = u.w * TEMP;
        } else {
            #pragma unroll
            for (int c = 0; c < 4; ++c)
                qT[qh][aq][c4*4+c] =
                    qf[(size_t)(b * 128 + qh * 16 + c4 * 4 + c) * 4096 + qpos] * TEMP;
        }
    }
    __syncthreads();

    {
        float sc[4];
        __builtin_amdgcn_s_setprio(1);
        #pragma unroll
        for (int q = 0; q < 4; ++q){
            const float4* qp = (const float4*)&qT[hh][q][0];
            float4 qa = qp[0], qb = qp[1], qc = qp[2], qd = qp[3];
            float s2 = 0.f;
            s2 = fmaf(qa.x, k[0],  s2); s2 = fmaf(qa.y, k[1],  s2);
            s2 = fmaf(qa.z, k[2],  s2); s2 = fmaf(qa.w, k[3],  s2);
            s2 = fmaf(qb.x, k[4],  s2); s2 = fmaf(qb.y, k[5],  s2);
            s2 = fmaf(qb.z, k[6],  s2); s2 = fmaf(qb.w, k[7],  s2);
            s2 = fmaf(qc.x, k[8],  s2); s2 = fmaf(qc.y, k[9],  s2);
            s2 = fmaf(qc.z, k[10], s2); s2 = fmaf(qc.w, k[11], s2);
            s2 = fmaf(qd.x, k[12], s2); s2 = fmaf(qd.y, k[13], s2);
            s2 = fmaf(qd.z, k[14], s2); s2 = fmaf(qd.w, k[15], s2);
            sc[q] = s2;
        }
        __builtin_amdgcn_s_setprio(0);
        #pragma unroll
        for (int q = 0; q < 4; ++q){
            float m = red16_max(sc[q]);
            m = fmaxf(m, sw16(m));               // 32-lane max (exact)
            float e = __expf(sc[q] - m);
            float s2 = red16_sum(e);
            s2 += sw16(s2);                      // 32-lane sum
            pT[hh][q][t] = e / s2;
        }
    }
    __syncthreads();

    {
        float mx = fmaxf(w0, w1);
        float e0 = __expf(w0 - mx), e1 = __expf(w1 - mx);
        float w0f = e0 / (e0 + e1), w1f = e1 / (e0 + e1);

        int q0 = (tid >> 4) & 1;
        int cpair = dd >> 1;
        int sh = (dd & 1) << 4;                  // 0: low half, 16: high half
        float a0 = 0.f, a1 = 0.f;
        __builtin_amdgcn_s_setprio(1);
        #pragma unroll
        for (int tt = 0; tt < 16; ++tt){
            uint2 uu = *(const uint2*)&vTp[hh][cpair][tt * 2];
            float v0 = __uint_as_float((uu.x >> sh) << 16);
            float v1 = __uint_as_float((uu.y >> sh) << 16);
            float2 pA = *(const float2*)&pT[hh][q0][tt * 2];
            float2 pB = *(const float2*)&pT[hh][q0 + 2][tt * 2];
            a0 = fmaf(pA.x, v0, a0); a0 = fmaf(pA.y, v1, a0);
            a1 = fmaf(pB.x, v0, a1); a1 = fmaf(pB.y, v1, a1);
        }
        __builtin_amdgcn_s_setprio(0);
        float o0 = w0f * m0 + w1f * a0;
        float o1 = w0f * m0 + w1f * a1;
        int posA = (2 * i) * 64 + 2 * j + q0;
        int posB = (2 * i + 1) * 64 + 2 * j + q0;
        out[(size_t)((b * 4096 + posA) * 8 + hh) * 16 + dd] = o0;
        out[(size_t)((b * 4096 + posB) * 8 + hh) * 16 + dd] = o1;
    }
}

extern "C" void kernel_launch(void* const* d_in, const int* in_sizes, int n_in,
                              void* d_out, int out_size, void* d_ws, size_t ws_size,
                              hipStream_t stream)
{
    (void)in_sizes; (void)n_in; (void)out_size;

    const float* q_fine   = (const float*)d_in[0];
    const float* q_coarse = (const float*)d_in[1];
    const float* k_fine   = (const float*)d_in[2];
    const float* k_coarse = (const float*)d_in[3];
    const float* v_fine   = (const float*)d_in[4];
    const float* v_coarse = (const float*)d_in[5];
    const float* weight   = (const float*)d_in[6];

    const size_t MB = 1024 * 1024;
    float*    msg0   = (float*)d_ws;                          // 2 MB
    int*      topk   = (int*)((char*)d_ws + 2 * MB);          // 1 MB
    float*    qT     = (float*)((char*)d_ws + 3 * MB);        // 8 MB
    uint32_t* packed = (uint32_t*)((char*)d_ws + 11 * MB);    // 8 MB
    uint4*    KP1    = (uint4*)((char*)d_ws + 19 * MB);       // 2 MB
    uint4*    KP3    = (uint4*)((char*)d_ws + 21 * MB);       // 2 MB
    uint4*    VP1    = (uint4*)((char*)d_ws + 23 * MB);       // 2 MB
    const int doT = (ws_size >= 19 * MB) ? 1 : 0;
    const int doM = (ws_size >= 25 * MB) ? 1 : 0;

    if (doM){
        pack_coarse<<<dim3(32, 2, 8), dim3(256), 0, stream>>>(k_coarse, v_coarse,
                                                              KP1, KP3, VP1);
        if (doT){
            coarse_fused<<<dim3(2816), dim3(256), 0, stream>>>(
                q_coarse, KP1, KP3, VP1, msg0, topk,
                k_fine, v_fine, q_fine, packed, qT);
        } else {
            coarse_mfma<<<dim3(64, 8, 4), dim3(256), 0, stream>>>(q_coarse, KP1, KP3,
                                                                  VP1, msg0, topk);
        }
    } else {
        coarse_kernel<<<dim3(32, 8, 4), dim3(512), 0, stream>>>(q_coarse, k_coarse,
                                                                v_coarse, msg0, topk);
        if (doT){
            pack_kernel<<<dim3(64, 4, 3), dim3(256), 0, stream>>>(k_fine, v_fine, q_fine,
                                                                  packed, qT);
        }
    }

    fine_kernel<<<dim3(1024, 4), dim3(256), 0, stream>>>(q_fine, k_fine, v_fine,
                                                         qT, packed, doT,
                                                         weight, topk, msg0,
                                                         (float*)d_out);
}